// Round 1
// baseline (121.983 us; speedup 1.0000x reference)
//
#include <hip/hip_runtime.h>
#include <math.h>

// BRF elementwise dynamics, fp32, B*D = 16.7M elems.
// out layout: [z | u_ | v_new | q_new], each N = B*D floats.

#define DTF ((float)(1.0 / 24000.0))   // matches float32(python DT)
#define QDECAY 0.9f

// --- per-column coefficient precompute: coef = [omega | pomega-|bs| | |thr|] ---
__global__ void brf_coef_kernel(const float* __restrict__ omegas,
                                const float* __restrict__ bs,
                                const float* __restrict__ threshold,
                                float* __restrict__ coef, int D) {
#pragma clang fp contract(off)
    int i = blockIdx.x * blockDim.x + threadIdx.x;
    if (i < D) {
        float om = fabsf(omegas[i]);
        float t  = DTF * om;                 // dt*omega
        float s  = sqrtf(1.0f - t * t);      // IEEE sqrt, matches np
        float p  = (-1.0f + s) / DTF;        // IEEE div
        coef[i]          = om;
        coef[D + i]      = p - fabsf(bs[i]); // (p_omega - |bs|); b = this - q
        coef[2 * D + i]  = fabsf(threshold[i]);
    }
}

__device__ __forceinline__ void brf_elem(float x, float u, float v, float q,
                                         float om, float pw, float th,
                                         float& z, float& u_, float& vn, float& qn) {
#pragma clang fp contract(off)
    float b  = pw - q;                                   // (p_omega-|bs|) - q
    // u_ = ((u + (b*u)*DT) - (om*v)*DT) + x*DT   (left-assoc, no FMA)
    float t1 = (b * u) * DTF;
    float t2 = (om * v) * DTF;
    float t3 = x * DTF;
    u_ = ((u + t1) - t2) + t3;
    // v_new = (v + (om*u)*DT) + (b*v)*DT
    float t4 = (om * u) * DTF;
    float t5 = (b * v) * DTF;
    vn = (v + t4) + t5;
    float s = (fabsf(u_) - th) - q;
    z  = (s > 0.0f) ? 1.0f : 0.0f;
    qn = q * QDECAY + z;
}

__global__ __launch_bounds__(256) void brf_main_kernel(
        const float4* __restrict__ x, const float4* __restrict__ u,
        const float4* __restrict__ v, const float4* __restrict__ q,
        const float* __restrict__ coef, float* __restrict__ out,
        int N4, int D4, int D) {
#pragma clang fp contract(off)
    const float4* omv = (const float4*)(coef);
    const float4* pwv = (const float4*)(coef + D);
    const float4* thv = (const float4*)(coef + 2 * D);
    float4* out_z = (float4*)out;
    float4* out_u = out_z + N4;
    float4* out_v = out_z + 2 * (size_t)N4;
    float4* out_q = out_z + 3 * (size_t)N4;

    const bool pow2 = (D4 & (D4 - 1)) == 0;
    int stride = gridDim.x * blockDim.x;
    for (int i = blockIdx.x * blockDim.x + threadIdx.x; i < N4; i += stride) {
        int c4 = pow2 ? (i & (D4 - 1)) : (i % D4);
        float4 xv = x[i], uv = u[i], vv = v[i], qv = q[i];
        float4 oc = omv[c4], pc = pwv[c4], tc = thv[c4];

        float4 rz, ru, rv, rq;
        brf_elem(xv.x, uv.x, vv.x, qv.x, oc.x, pc.x, tc.x, rz.x, ru.x, rv.x, rq.x);
        brf_elem(xv.y, uv.y, vv.y, qv.y, oc.y, pc.y, tc.y, rz.y, ru.y, rv.y, rq.y);
        brf_elem(xv.z, uv.z, vv.z, qv.z, oc.z, pc.z, tc.z, rz.z, ru.z, rv.z, rq.z);
        brf_elem(xv.w, uv.w, vv.w, qv.w, oc.w, pc.w, tc.w, rz.w, ru.w, rv.w, rq.w);

        out_z[i] = rz;
        out_u[i] = ru;
        out_v[i] = rv;
        out_q[i] = rq;
    }
}

extern "C" void kernel_launch(void* const* d_in, const int* in_sizes, int n_in,
                              void* d_out, int out_size, void* d_ws, size_t ws_size,
                              hipStream_t stream) {
    const float* x   = (const float*)d_in[0];
    const float* u   = (const float*)d_in[1];
    const float* v   = (const float*)d_in[2];
    const float* q   = (const float*)d_in[3];
    const float* om  = (const float*)d_in[4];
    const float* bs  = (const float*)d_in[5];
    const float* th  = (const float*)d_in[6];
    float* out = (float*)d_out;
    float* coef = (float*)d_ws;          // 3*D floats

    int N = in_sizes[0];                 // B*D
    int D = in_sizes[4];
    int N4 = N / 4;
    int D4 = D / 4;

    brf_coef_kernel<<<(D + 255) / 256, 256, 0, stream>>>(om, bs, th, coef, D);

    int blocks = (N4 + 255) / 256;
    if (blocks > 2048) blocks = 2048;
    brf_main_kernel<<<blocks, 256, 0, stream>>>(
        (const float4*)x, (const float4*)u, (const float4*)v, (const float4*)q,
        coef, out, N4, D4, D);
}

// Round 3
// 103.372 us; speedup vs baseline: 1.1800x; 1.1800x over previous
//
#include <hip/hip_runtime.h>
#include <math.h>

// BRF elementwise dynamics, fp32, B*D elems.
// out layout: [z | u_ | v_new | q_new], each N = B*D floats.
// Single fused kernel: per-thread column coefficients computed once
// (grid stride is a multiple of D4, so each thread's column is fixed).

#define DTF ((float)(1.0 / 24000.0))
#define QDECAY 0.9f

typedef float f32x4 __attribute__((ext_vector_type(4)));

__device__ __forceinline__ void brf_elem(float x, float u, float v, float q,
                                         float om, float pw, float th,
                                         float& z, float& u_, float& vn, float& qn) {
#pragma clang fp contract(off)
    float b  = pw - q;                                   // (p_omega-|bs|) - q
    // u_ = ((u + (b*u)*DT) - (om*v)*DT) + x*DT   (left-assoc, no FMA)
    float t1 = (b * u) * DTF;
    float t2 = (om * v) * DTF;
    float t3 = x * DTF;
    u_ = ((u + t1) - t2) + t3;
    // v_new = (v + (om*u)*DT) + (b*v)*DT
    float t4 = (om * u) * DTF;
    float t5 = (b * v) * DTF;
    vn = (v + t4) + t5;
    float s = (fabsf(u_) - th) - q;
    z  = (s > 0.0f) ? 1.0f : 0.0f;
    qn = q * QDECAY + z;
}

__global__ __launch_bounds__(256) void brf_fused_kernel(
        const f32x4* __restrict__ x, const f32x4* __restrict__ u,
        const f32x4* __restrict__ v, const f32x4* __restrict__ q,
        const float* __restrict__ omegas, const float* __restrict__ bs,
        const float* __restrict__ threshold, float* __restrict__ out,
        int N4, int D4) {
#pragma clang fp contract(off)
    f32x4* out_z = (f32x4*)out;
    f32x4* out_u = out_z + (size_t)N4;
    f32x4* out_v = out_z + 2 * (size_t)N4;
    f32x4* out_q = out_z + 3 * (size_t)N4;

    const int tid    = blockIdx.x * blockDim.x + threadIdx.x;
    const int stride = gridDim.x * blockDim.x;  // launcher guarantees stride % D4 == 0
    const int c4     = tid % D4;                // constant across all loop iterations

    // --- per-column coefficients, computed ONCE per thread (IEEE, matches np) ---
    f32x4 o4 = ((const f32x4*)omegas)[c4];
    f32x4 b4 = ((const f32x4*)bs)[c4];
    f32x4 h4 = ((const f32x4*)threshold)[c4];
    float oc[4], pw[4], tc[4];
#pragma unroll
    for (int k = 0; k < 4; ++k) {
        float om = fabsf(o4[k]);
        float t  = DTF * om;
        float tt = t * t;                 // jnp.square
        float s  = sqrtf(1.0f - tt);      // IEEE sqrt
        float p  = (-1.0f + s) / DTF;     // IEEE div
        oc[k] = om;
        pw[k] = p - fabsf(b4[k]);
        tc[k] = fabsf(h4[k]);
    }

    for (int i = tid; i < N4; i += stride) {
        f32x4 xv = __builtin_nontemporal_load(&x[i]);
        f32x4 uv = __builtin_nontemporal_load(&u[i]);
        f32x4 vv = __builtin_nontemporal_load(&v[i]);
        f32x4 qv = __builtin_nontemporal_load(&q[i]);

        f32x4 rz, ru, rv, rq;
#pragma unroll
        for (int k = 0; k < 4; ++k) {
            float z, u_, vn, qn;
            brf_elem(xv[k], uv[k], vv[k], qv[k], oc[k], pw[k], tc[k],
                     z, u_, vn, qn);
            rz[k] = z; ru[k] = u_; rv[k] = vn; rq[k] = qn;
        }

        __builtin_nontemporal_store(rz, &out_z[i]);
        __builtin_nontemporal_store(ru, &out_u[i]);
        __builtin_nontemporal_store(rv, &out_v[i]);
        __builtin_nontemporal_store(rq, &out_q[i]);
    }
}

extern "C" void kernel_launch(void* const* d_in, const int* in_sizes, int n_in,
                              void* d_out, int out_size, void* d_ws, size_t ws_size,
                              hipStream_t stream) {
    const float* x   = (const float*)d_in[0];
    const float* u   = (const float*)d_in[1];
    const float* v   = (const float*)d_in[2];
    const float* q   = (const float*)d_in[3];
    const float* om  = (const float*)d_in[4];
    const float* bs  = (const float*)d_in[5];
    const float* th  = (const float*)d_in[6];
    float* out = (float*)d_out;

    int N  = in_sizes[0];   // B*D
    int D  = in_sizes[4];
    int N4 = N / 4;
    int D4 = D / 4;

    int blocks = (N4 + 255) / 256;
    if (blocks > 2048) blocks = 2048;
    // Round blocks up so stride (= blocks*256 float4s) is a multiple of D4,
    // making each thread's column index invariant across grid-stride iterations.
    {
        int g = 256, b = D4;            // gcd(256, D4)
        while (b) { int t = g % b; g = b; b = t; }
        int m = D4 / g;                 // blocks must be a multiple of m
        blocks = ((blocks + m - 1) / m) * m;
    }

    brf_fused_kernel<<<blocks, 256, 0, stream>>>(
        (const f32x4*)x, (const f32x4*)u, (const f32x4*)v, (const f32x4*)q,
        om, bs, th, out, N4, D4);
}

// Round 4
// 100.859 us; speedup vs baseline: 1.2094x; 1.0249x over previous
//
#include <hip/hip_runtime.h>
#include <math.h>

// BRF elementwise dynamics, fp32, B*D elems.
// out layout: [z | u_ | v_new | q_new], each N = B*D floats.
// Single fused kernel, unroll x2 over grid-stride steps: 8 loads in flight
// before any compute. Column coefficients computed once per thread
// (stride % D4 == 0 guaranteed by launcher).

#define DTF ((float)(1.0 / 24000.0))
#define QDECAY 0.9f

typedef float f32x4 __attribute__((ext_vector_type(4)));

__device__ __forceinline__ void brf_elem(float x, float u, float v, float q,
                                         float om, float pw, float th,
                                         float& z, float& u_, float& vn, float& qn) {
#pragma clang fp contract(off)
    float b  = pw - q;                                   // (p_omega-|bs|) - q
    float t1 = (b * u) * DTF;
    float t2 = (om * v) * DTF;
    float t3 = x * DTF;
    u_ = ((u + t1) - t2) + t3;
    float t4 = (om * u) * DTF;
    float t5 = (b * v) * DTF;
    vn = (v + t4) + t5;
    float s = (fabsf(u_) - th) - q;
    z  = (s > 0.0f) ? 1.0f : 0.0f;
    qn = q * QDECAY + z;
}

__global__ __launch_bounds__(256) void brf_fused_kernel(
        const f32x4* __restrict__ x, const f32x4* __restrict__ u,
        const f32x4* __restrict__ v, const f32x4* __restrict__ q,
        const float* __restrict__ omegas, const float* __restrict__ bs,
        const float* __restrict__ threshold, float* __restrict__ out,
        int N4, int D4) {
#pragma clang fp contract(off)
    f32x4* out_z = (f32x4*)out;
    f32x4* out_u = out_z + (size_t)N4;
    f32x4* out_v = out_z + 2 * (size_t)N4;
    f32x4* out_q = out_z + 3 * (size_t)N4;

    const int tid    = blockIdx.x * blockDim.x + threadIdx.x;
    const int stride = gridDim.x * blockDim.x;  // launcher guarantees stride % D4 == 0
    const int c4     = tid % D4;                // constant across all loop iterations

    // --- per-column coefficients, computed ONCE per thread (IEEE, matches np) ---
    f32x4 o4 = ((const f32x4*)omegas)[c4];
    f32x4 b4 = ((const f32x4*)bs)[c4];
    f32x4 h4 = ((const f32x4*)threshold)[c4];
    float oc[4], pw[4], tc[4];
#pragma unroll
    for (int k = 0; k < 4; ++k) {
        float om = fabsf(o4[k]);
        float t  = DTF * om;
        float tt = t * t;                 // jnp.square
        float s  = sqrtf(1.0f - tt);      // IEEE sqrt
        float p  = (-1.0f + s) / DTF;     // IEEE div
        oc[k] = om;
        pw[k] = p - fabsf(b4[k]);
        tc[k] = fabsf(h4[k]);
    }

    int i = tid;
    // main: two grid-stride steps per iteration, all 8 loads issued up front
    for (; i + stride < N4; i += 2 * stride) {
        int j = i + stride;
        f32x4 xa = __builtin_nontemporal_load(&x[i]);
        f32x4 ua = __builtin_nontemporal_load(&u[i]);
        f32x4 va = __builtin_nontemporal_load(&v[i]);
        f32x4 qa = __builtin_nontemporal_load(&q[i]);
        f32x4 xb = __builtin_nontemporal_load(&x[j]);
        f32x4 ub = __builtin_nontemporal_load(&u[j]);
        f32x4 vb = __builtin_nontemporal_load(&v[j]);
        f32x4 qb = __builtin_nontemporal_load(&q[j]);

        f32x4 rza, rua, rva, rqa, rzb, rub, rvb, rqb;
#pragma unroll
        for (int k = 0; k < 4; ++k) {
            float z, u_, vn, qn;
            brf_elem(xa[k], ua[k], va[k], qa[k], oc[k], pw[k], tc[k], z, u_, vn, qn);
            rza[k] = z; rua[k] = u_; rva[k] = vn; rqa[k] = qn;
        }
        __builtin_nontemporal_store(rza, &out_z[i]);
        __builtin_nontemporal_store(rua, &out_u[i]);
        __builtin_nontemporal_store(rva, &out_v[i]);
        __builtin_nontemporal_store(rqa, &out_q[i]);

#pragma unroll
        for (int k = 0; k < 4; ++k) {
            float z, u_, vn, qn;
            brf_elem(xb[k], ub[k], vb[k], qb[k], oc[k], pw[k], tc[k], z, u_, vn, qn);
            rzb[k] = z; rub[k] = u_; rvb[k] = vn; rqb[k] = qn;
        }
        __builtin_nontemporal_store(rzb, &out_z[j]);
        __builtin_nontemporal_store(rub, &out_u[j]);
        __builtin_nontemporal_store(rvb, &out_v[j]);
        __builtin_nontemporal_store(rqb, &out_q[j]);
    }
    // tail: at most one remaining grid-stride step
    for (; i < N4; i += stride) {
        f32x4 xv = __builtin_nontemporal_load(&x[i]);
        f32x4 uv = __builtin_nontemporal_load(&u[i]);
        f32x4 vv = __builtin_nontemporal_load(&v[i]);
        f32x4 qv = __builtin_nontemporal_load(&q[i]);
        f32x4 rz, ru, rv, rq;
#pragma unroll
        for (int k = 0; k < 4; ++k) {
            float z, u_, vn, qn;
            brf_elem(xv[k], uv[k], vv[k], qv[k], oc[k], pw[k], tc[k], z, u_, vn, qn);
            rz[k] = z; ru[k] = u_; rv[k] = vn; rq[k] = qn;
        }
        __builtin_nontemporal_store(rz, &out_z[i]);
        __builtin_nontemporal_store(ru, &out_u[i]);
        __builtin_nontemporal_store(rv, &out_v[i]);
        __builtin_nontemporal_store(rq, &out_q[i]);
    }
}

extern "C" void kernel_launch(void* const* d_in, const int* in_sizes, int n_in,
                              void* d_out, int out_size, void* d_ws, size_t ws_size,
                              hipStream_t stream) {
    const float* x   = (const float*)d_in[0];
    const float* u   = (const float*)d_in[1];
    const float* v   = (const float*)d_in[2];
    const float* q   = (const float*)d_in[3];
    const float* om  = (const float*)d_in[4];
    const float* bs  = (const float*)d_in[5];
    const float* th  = (const float*)d_in[6];
    float* out = (float*)d_out;

    int N  = in_sizes[0];   // B*D
    int D  = in_sizes[4];
    int N4 = N / 4;
    int D4 = D / 4;

    int blocks = (N4 + 255) / 256;
    if (blocks > 2048) blocks = 2048;
    // Round blocks up so stride (= blocks*256 float4s) is a multiple of D4,
    // making each thread's column index invariant across grid-stride iterations.
    {
        int g = 256, b = D4;            // gcd(256, D4)
        while (b) { int t = g % b; g = b; b = t; }
        int m = D4 / g;                 // blocks must be a multiple of m
        blocks = ((blocks + m - 1) / m) * m;
    }

    brf_fused_kernel<<<blocks, 256, 0, stream>>>(
        (const f32x4*)x, (const f32x4*)u, (const f32x4*)v, (const f32x4*)q,
        om, bs, th, out, N4, D4);
}